// Round 15
// baseline (219.138 us; speedup 1.0000x reference)
//
#include <hip/hip_runtime.h>
#include <hip/hip_bf16.h>
#include <math.h>
#include <stdint.h>

#define SEQ 1024
#define CDIM 1024
#define NHEAD 16
#define HIDDEN 4096
#define BATCH 4
#define MROWS (BATCH*SEQ)   // 4096

using bf16x8 = __attribute__((ext_vector_type(8))) short;
using f32x4  = __attribute__((ext_vector_type(4))) float;

__device__ __forceinline__ short f2bf(float f) {
    union { float f; uint32_t u; } c; c.f = f;
    const uint32_t u = c.u + 0x7FFFu + ((c.u >> 16) & 1u);
    return (short)(u >> 16);
}

__device__ __forceinline__ float gelu_exact(float v) {
    return 0.5f * v * (1.0f + erff(v * 0.70710678118654752440f));
}

__device__ __forceinline__ void gload_lds16(const short* g, short* lds) {
    __builtin_amdgcn_global_load_lds(
        (const __attribute__((address_space(1))) void*)(uintptr_t)g,
        (__attribute__((address_space(3))) void*)(uintptr_t)lds,
        16, 0, 0);
}

// ---------------- merged weight fp32 -> bf16 conversion ----------------
__global__ void cvt_all_kernel(const float* __restrict__ qkv_w, const float* __restrict__ proj_w,
                               const float* __restrict__ fc1_w, const float* __restrict__ fc2_w,
                               short* __restrict__ wq, short* __restrict__ wp,
                               short* __restrict__ w1, short* __restrict__ w2) {
    const int blk = blockIdx.x;          // 6144 blocks x 256 thr x 8 elems
    const float* in; short* out; size_t base;
    if (blk < 1536)      { in = qkv_w;  out = wq; base = (size_t)blk * 2048; }
    else if (blk < 2048) { in = proj_w; out = wp; base = (size_t)(blk - 1536) * 2048; }
    else if (blk < 4096) { in = fc1_w;  out = w1; base = (size_t)(blk - 2048) * 2048; }
    else                 { in = fc2_w;  out = w2; base = (size_t)(blk - 4096) * 2048; }
    const size_t i = base + (size_t)threadIdx.x * 8;
    const float4 a = *(const float4*)(in + i);
    const float4 b = *(const float4*)(in + i + 4);
    bf16x8 s;
    s[0] = f2bf(a.x); s[1] = f2bf(a.y); s[2] = f2bf(a.z); s[3] = f2bf(a.w);
    s[4] = f2bf(b.x); s[5] = f2bf(b.y); s[6] = f2bf(b.z); s[7] = f2bf(b.w);
    *(bf16x8*)(out + i) = s;
}

// ---------------- LayerNorm ----------------
__global__ void ln_kernel(const float* __restrict__ x, const float* __restrict__ w,
                          const float* __restrict__ b, short* __restrict__ out) {
    const int row = blockIdx.x;
    const int t = threadIdx.x;
    const float4* xr = (const float4*)(x + (size_t)row * CDIM);
    float4 v = xr[t];
    float s  = v.x + v.y + v.z + v.w;
    float sq = v.x*v.x + v.y*v.y + v.z*v.z + v.w*v.w;
    #pragma unroll
    for (int off = 32; off; off >>= 1) {
        s  += __shfl_down(s, off);
        sq += __shfl_down(sq, off);
    }
    __shared__ float ss[4], ssq[4];
    const int wid = t >> 6, lane = t & 63;
    if (lane == 0) { ss[wid] = s; ssq[wid] = sq; }
    __syncthreads();
    s  = ss[0] + ss[1] + ss[2] + ss[3];
    sq = ssq[0] + ssq[1] + ssq[2] + ssq[3];
    const float mu  = s * (1.0f / CDIM);
    const float var = sq * (1.0f / CDIM) - mu * mu;
    const float rs  = rsqrtf(var + 1e-5f);
    const float4 wv = ((const float4*)w)[t];
    const float4 bv = ((const float4*)b)[t];
    short4 o;
    o.x = f2bf((v.x - mu) * rs * wv.x + bv.x);
    o.y = f2bf((v.y - mu) * rs * wv.y + bv.y);
    o.z = f2bf((v.z - mu) * rs * wv.z + bv.z);
    o.w = f2bf((v.w - mu) * rs * wv.w + bv.w);
    *(short4*)(out + (size_t)row * CDIM + t * 4) = o;
}

// ===== bf16 MFMA GEMM: BMxBN tile, 256 thr / 4 waves (2x2), 3-buffer
// counted-vmcnt loop, LDS swizzle both sides. NO sched_barrier (m141:
// order-pinning = 510 TF; compiler handles ds_read->MFMA lgkm itself).
template<int BM, int BN, bool BIAS, bool RES, bool GELU_, bool OUTBF16>
__global__ __launch_bounds__(256) void mgemm(
    const short* __restrict__ A, const short* __restrict__ B,
    const float* __restrict__ bias, const float* __restrict__ res,
    void* __restrict__ Cv, int M, int N, int K)
{
    constexpr int MF = BM / 32;          // frags per wave (M)
    constexpr int NF = BN / 32;          // frags per wave (N)
    constexpr int CA = BM / 64;          // A gload chunks per wave
    constexpr int CB = BN / 64;          // B gload chunks per wave
    __shared__ __align__(16) short As[3][BM * 32];
    __shared__ __align__(16) short Bs[3][BN * 32];
    const int t = threadIdx.x;
    const int w = t >> 6, l = t & 63;

    const int gx = gridDim.x;
    const int nwg = gx * gridDim.y;
    const int lid = blockIdx.y * gx + blockIdx.x;
    const int swzb = (lid & 7) * (nwg >> 3) + (lid >> 3);
    const int bx = swzb % gx, by = swzb / gx;
    const int m0 = by * BM, n0 = bx * BN;

    const int wrow = (w >> 1) * (BM / 2);
    const int wcol = (w & 1) * (BN / 2);

    const int sk8 = ((l & 3) ^ ((l >> 3) & 3)) * 8;
    const short* agp = A + (size_t)(m0 + w * 16 * CA + (l >> 2)) * K + sk8;
    const short* bgp = B + (size_t)(n0 + w * 16 * CB + (l >> 2)) * K + sk8;

    const int fr = l & 15;
    const int rk = ((l >> 4) ^ ((fr >> 1) & 3)) * 8;
    int aoff[MF], boff[NF];
    #pragma unroll
    for (int m = 0; m < MF; ++m) aoff[m] = (wrow + m * 16 + fr) * 32 + rk;
    #pragma unroll
    for (int n = 0; n < NF; ++n) boff[n] = (wcol + n * 16 + fr) * 32 + rk;

    auto stage = [&](int k0, int buf) {
        #pragma unroll
        for (int c = 0; c < CA; ++c)
            gload_lds16(agp + (size_t)(c * 16) * K + k0, &As[buf][(w * CA + c) * 512]);
        #pragma unroll
        for (int c = 0; c < CB; ++c)
            gload_lds16(bgp + (size_t)(c * 16) * K + k0, &Bs[buf][(w * CB + c) * 512]);
    };

    f32x4 acc[MF][NF] = {};
    const int T = K / 32;
    stage(0, 0);
    stage(32, 1);
    int cur = 0;
    for (int kt = 0; kt < T; ++kt) {
        if (kt < T - 1) {
            if constexpr (CA + CB == 4) asm volatile("s_waitcnt vmcnt(4)" ::: "memory");
            else                        asm volatile("s_waitcnt vmcnt(3)" ::: "memory");
        } else {
            asm volatile("s_waitcnt vmcnt(0)" ::: "memory");
        }
        __builtin_amdgcn_s_barrier();
        if (kt + 2 < T) {
            int nb = kt + 2; nb -= (nb >= 3) ? ((nb / 3) * 3) : 0;   // (kt+2)%3
            stage((kt + 2) * 32, nb);
        }
        bf16x8 af[MF], bfr[NF];
        #pragma unroll
        for (int m = 0; m < MF; ++m) af[m]  = *(const bf16x8*)&As[cur][aoff[m]];
        #pragma unroll
        for (int n = 0; n < NF; ++n) bfr[n] = *(const bf16x8*)&Bs[cur][boff[n]];
        #pragma unroll
        for (int m = 0; m < MF; ++m)
            #pragma unroll
            for (int n = 0; n < NF; ++n)
                acc[m][n] = __builtin_amdgcn_mfma_f32_16x16x32_bf16(af[m], bfr[n], acc[m][n], 0, 0, 0);
        cur = (cur == 2) ? 0 : cur + 1;
    }

    const int lr4 = (l >> 4) * 4, lc = l & 15;
    #pragma unroll
    for (int m = 0; m < MF; ++m) {
        #pragma unroll
        for (int n = 0; n < NF; ++n) {
            const int col = n0 + wcol + n * 16 + lc;
            const float bv = BIAS ? bias[col] : 0.0f;
            #pragma unroll
            for (int r = 0; r < 4; ++r) {
                const int row = m0 + wrow + m * 16 + lr4 + r;
                float v = acc[m][n][r] + bv;
                if (GELU_) v = gelu_exact(v);
                if (RES)   v += res[(size_t)row * N + col];
                if (OUTBF16) ((short*)Cv)[(size_t)row * N + col] = f2bf(v);
                else         ((float*)Cv)[(size_t)row * N + col] = v;
            }
        }
    }
}

// ===== QKV GEMM: 128x128 mgemm body + Q/K/V epilogue (grid 24x32 = 768) =====
__global__ __launch_bounds__(256) void qkv_m(
    const short* __restrict__ A, const short* __restrict__ B,
    short* __restrict__ qkvb, short* __restrict__ VT, int K)
{
    __shared__ __align__(16) short As[3][128 * 32];
    __shared__ __align__(16) short Bs[3][128 * 32];
    const int t = threadIdx.x;
    const int w = t >> 6, l = t & 63;

    const int gx = gridDim.x;                 // 24
    const int nwg = gx * gridDim.y;           // 768
    const int lid = blockIdx.y * gx + blockIdx.x;
    const int swzb = (lid & 7) * (nwg >> 3) + (lid >> 3);
    const int bx = swzb % gx, by = swzb / gx;
    const int m0 = by * 128, n0 = bx * 128;

    const int wrow = (w >> 1) * 64;
    const int wcol = (w & 1) * 64;

    const int sk8 = ((l & 3) ^ ((l >> 3) & 3)) * 8;
    const short* agp = A + (size_t)(m0 + w * 32 + (l >> 2)) * K + sk8;
    const short* bgp = B + (size_t)(n0 + w * 32 + (l >> 2)) * K + sk8;

    const int fr = l & 15;
    const int rk = ((l >> 4) ^ ((fr >> 1) & 3)) * 8;
    int aoff[4], boff[4];
    #pragma unroll
    for (int m = 0; m < 4; ++m) aoff[m] = (wrow + m * 16 + fr) * 32 + rk;
    #pragma unroll
    for (int n = 0; n < 4; ++n) boff[n] = (wcol + n * 16 + fr) * 32 + rk;

    auto stage = [&](int k0, int buf) {
        #pragma unroll
        for (int c = 0; c < 2; ++c)
            gload_lds16(agp + (size_t)(c * 16) * K + k0, &As[buf][(w * 2 + c) * 512]);
        #pragma unroll
        for (int c = 0; c < 2; ++c)
            gload_lds16(bgp + (size_t)(c * 16) * K + k0, &Bs[buf][(w * 2 + c) * 512]);
    };

    f32x4 acc[4][4] = {};
    const int T = K / 32;
    stage(0, 0);
    stage(32, 1);
    int cur = 0;
    for (int kt = 0; kt < T; ++kt) {
        if (kt < T - 1) asm volatile("s_waitcnt vmcnt(4)" ::: "memory");
        else            asm volatile("s_waitcnt vmcnt(0)" ::: "memory");
        __builtin_amdgcn_s_barrier();
        if (kt + 2 < T) {
            int nb = kt + 2; nb -= (nb >= 3) ? ((nb / 3) * 3) : 0;
            stage((kt + 2) * 32, nb);
        }
        bf16x8 af[4], bfr[4];
        #pragma unroll
        for (int m = 0; m < 4; ++m) af[m]  = *(const bf16x8*)&As[cur][aoff[m]];
        #pragma unroll
        for (int n = 0; n < 4; ++n) bfr[n] = *(const bf16x8*)&Bs[cur][boff[n]];
        #pragma unroll
        for (int m = 0; m < 4; ++m)
            #pragma unroll
            for (int n = 0; n < 4; ++n)
                acc[m][n] = __builtin_amdgcn_mfma_f32_16x16x32_bf16(af[m], bfr[n], acc[m][n], 0, 0, 0);
        cur = (cur == 2) ? 0 : cur + 1;
    }

    const int lr4 = (l >> 4) * 4, lc = l & 15;
    if (n0 < 2048) {
        const float sc = (n0 < 1024) ? 0.125f : 1.0f;
        #pragma unroll
        for (int m = 0; m < 4; ++m) {
            #pragma unroll
            for (int n = 0; n < 4; ++n) {
                const int col = n0 + wcol + n * 16 + lc;
                #pragma unroll
                for (int r = 0; r < 4; ++r) {
                    const int row = m0 + wrow + m * 16 + lr4 + r;
                    qkvb[(size_t)row * 2048 + col] = f2bf(acc[m][n][r] * sc);
                }
            }
        }
    } else {
        #pragma unroll
        for (int m = 0; m < 4; ++m) {
            const int row0 = m0 + wrow + m * 16 + lr4;   // 4-aligned
            const int b = row0 >> 10, nseq = row0 & 1023;
            #pragma unroll
            for (int n = 0; n < 4; ++n) {
                const int c2 = n0 - 2048 + wcol + n * 16 + lc;
                const int h = c2 >> 6, d = c2 & 63;
                short4 v4;
                v4.x = f2bf(acc[m][n][0]); v4.y = f2bf(acc[m][n][1]);
                v4.z = f2bf(acc[m][n][2]); v4.w = f2bf(acc[m][n][3]);
                *(short4*)&VT[(((size_t)(b * 16 + h) * 64 + d) * 1024) + nseq] = v4;
            }
        }
    }
}

// ---------------- MFMA flash attention: QBLK=128, 8 waves, 512 blocks ----------------
__global__ __launch_bounds__(512) void fattn(const short* __restrict__ qkvb,
                                             const short* __restrict__ VT,
                                             short* __restrict__ o) {
    const int lid = blockIdx.y * gridDim.x + blockIdx.x;   // grid (8,64) = 512
    const int bh = ((lid >> 6) << 3) | (lid & 7);
    const int q0 = ((lid >> 3) & 7) * 128;
    const int b = bh >> 4, h = bh & 15;
    const int t = threadIdx.x, w = t >> 6, l = t & 63;

    __shared__ __align__(16) short Ks[2][64 * 64];
    __shared__ __align__(16) short Vs[2][64 * 64];
    __shared__ __align__(16) short Ps[8][1024];

    const size_t qrow = (size_t)(b * SEQ + q0 + w * 16 + (l & 15)) * 2048 + h * 64;
    bf16x8 qf[2];
    qf[0] = *(const bf16x8*)&qkvb[qrow + (l >> 4) * 8];
    qf[1] = *(const bf16x8*)&qkvb[qrow + 32 + (l >> 4) * 8];

    const int srow = l >> 3;
    const int sc16 = (l & 7) ^ (srow & 7);
    const short* Kg = qkvb + 1024 + h * 64;
    const short* Vg = VT + (size_t)bh * 64 * 1024;

    f32x4 acc[4] = {};
    float mr = -1e30f, lr = 0.0f;
    const int q = l & 15;
    const int g4 = (l >> 4) & 3;

    auto stage = [&](int kt, int buf) {
        const int kv0 = kt * 64;
        const int r0 = w * 8;
        gload_lds16(Kg + (size_t)(b * SEQ + kv0 + r0 + srow) * 2048 + sc16 * 8,
                    &Ks[buf][r0 * 64]);
        gload_lds16(Vg + (size_t)(r0 + srow) * 1024 + kv0 + sc16 * 8,
                    &Vs[buf][r0 * 64]);
    };

    stage(0, 0);
    for (int kt = 0; kt < 16; ++kt) {
        const int cur = kt & 1;
        __syncthreads();
        if (kt + 1 < 16) stage(kt + 1, cur ^ 1);

        f32x4 sacc[4];
        #pragma unroll
        for (int nt = 0; nt < 4; ++nt) {
            f32x4 z = {};
            #pragma unroll
            for (int ks = 0; ks < 2; ++ks) {
                const int row = nt * 16 + (l & 15);
                const int c16 = (ks * 4 + (l >> 4)) ^ (row & 7);
                const bf16x8 kf = *(const bf16x8*)&Ks[cur][row * 64 + c16 * 8];
                z = __builtin_amdgcn_mfma_f32_16x16x32_bf16(kf, qf[ks], z, 0, 0, 0);
            }
            sacc[nt] = z;
        }
        float tm = sacc[0][0];
        #pragma unroll
        for (int nt = 0; nt < 4; ++nt)
            #pragma unroll
            for (int r = 0; r < 4; ++r) tm = fmaxf(tm, sacc[nt][r]);
        tm = fmaxf(tm, __shfl_xor(tm, 16));
        tm = fmaxf(tm, __shfl_xor(tm, 32));
        const bool norescale = __all(tm <= mr + 8.0f);
        float fac = 1.0f;
        if (!norescale) {
            const float nm = fmaxf(mr, tm);
            fac = __expf(mr - nm);
            mr = nm;
        }
        float p[4][4];
        float ts = 0.0f;
        #pragma unroll
        for (int nt = 0; nt < 4; ++nt)
            #pragma unroll
            for (int r = 0; r < 4; ++r) {
                p[nt][r] = __expf(sacc[nt][r] - mr);
                ts += p[nt][r];
            }
        ts += __shfl_xor(ts, 16);
        ts += __shfl_xor(ts, 32);
        lr = lr * fac + ts;
        if (!norescale) {
            float facv[4];
            #pragma unroll
            for (int r = 0; r < 4; ++r)
                facv[r] = __shfl(fac, (l & 48) + g4 * 4 + r);
            #pragma unroll
            for (int nt2 = 0; nt2 < 4; ++nt2)
                #pragma unroll
                for (int r = 0; r < 4; ++r)
                    acc[nt2][r] *= facv[r];
        }
        #pragma unroll
        for (int nt = 0; nt < 4; ++nt) {
            uint32_t lo, hi;
            asm("v_cvt_pk_bf16_f32 %0, %1, %2" : "=v"(lo) : "v"(p[nt][0]), "v"(p[nt][1]));
            asm("v_cvt_pk_bf16_f32 %0, %1, %2" : "=v"(hi) : "v"(p[nt][2]), "v"(p[nt][3]));
            const int kvb = nt * 16 + g4 * 4;
            const int addr = q * 64 + (((kvb >> 3) ^ (q & 7)) << 3) + (kvb & 7);
            *(uint2*)&Ps[w][addr] = make_uint2(lo, hi);
        }
        asm volatile("s_waitcnt lgkmcnt(0)" ::: "memory");
        #pragma unroll
        for (int ks = 0; ks < 2; ++ks) {
            const int ql = l & 15;
            const bf16x8 pa = *(const bf16x8*)&Ps[w][ql * 64 + ((ks * 32 + (l >> 4) * 8) ^ ((ql & 7) << 3))];
            #pragma unroll
            for (int nt2 = 0; nt2 < 4; ++nt2) {
                const int row = nt2 * 16 + (l & 15);
                const int c16 = (ks * 4 + (l >> 4)) ^ (row & 7);
                const bf16x8 vf = *(const bf16x8*)&Vs[cur][row * 64 + c16 * 8];
                acc[nt2] = __builtin_amdgcn_mfma_f32_16x16x32_bf16(pa, vf, acc[nt2], 0, 0, 0);
            }
        }
    }
    float rcpl = 1.0f / lr;
    #pragma unroll
    for (int r = 0; r < 4; ++r) {
        const float rcp = __shfl(rcpl, (l & 48) + g4 * 4 + r);
        const int qq = q0 + w * 16 + g4 * 4 + r;
        #pragma unroll
        for (int nt2 = 0; nt2 < 4; ++nt2) {
            const int d = nt2 * 16 + (l & 15);
            o[(size_t)(b * SEQ + qq) * CDIM + h * 64 + d] = f2bf(acc[nt2][r] * rcp);
        }
    }
}

extern "C" void kernel_launch(void* const* d_in, const int* in_sizes, int n_in,
                              void* d_out, int out_size, void* d_ws, size_t ws_size,
                              hipStream_t stream) {
    const float* x      = (const float*)d_in[0];
    const float* ln1_w  = (const float*)d_in[1];
    const float* ln1_b  = (const float*)d_in[2];
    const float* qkv_w  = (const float*)d_in[3];
    const float* proj_w = (const float*)d_in[4];
    const float* proj_b = (const float*)d_in[5];
    const float* ln2_w  = (const float*)d_in[6];
    const float* ln2_b  = (const float*)d_in[7];
    const float* fc1_w  = (const float*)d_in[8];
    const float* fc1_b  = (const float*)d_in[9];
    const float* fc2_w  = (const float*)d_in[10];
    const float* fc2_b  = (const float*)d_in[11];
    float* out = (float*)d_out;

    short* ws16  = (short*)d_ws;
    short* wqkv  = ws16;
    short* wproj = ws16 + 3145728;
    short* wfc1  = ws16 + 4194304;
    short* wfc2  = ws16 + 8388608;
    char*  wsb   = (char*)d_ws;
    short* qkvb  = (short*)(wsb + (size_t)24 * 1024 * 1024);
    short* VT    = (short*)(wsb + (size_t)40 * 1024 * 1024);
    short* mlp1  = (short*)(wsb + (size_t)24 * 1024 * 1024);
    short* hbuf  = (short*)(wsb + (size_t)72 * 1024 * 1024);

    cvt_all_kernel<<<6144, 256, 0, stream>>>(qkv_w, proj_w, fc1_w, fc2_w,
                                             wqkv, wproj, wfc1, wfc2);

    ln_kernel<<<MROWS, 256, 0, stream>>>(x, ln1_w, ln1_b, hbuf);
    // QKV: 128x128, grid 24x32 = 768 blocks
    qkv_m<<<dim3(24, 32), 256, 0, stream>>>(hbuf, wqkv, qkvb, VT, 1024);
    // attention: QBLK=128, 512 thr, grid 8x64 = 512 blocks
    fattn<<<dim3(8, 64), 512, 0, stream>>>(qkvb, VT, hbuf);
    // proj: 64x128, grid 8x64 = 512 blocks
    mgemm<64,128,true,true,false,false><<<dim3(8, 64), 256, 0, stream>>>(
        hbuf, wproj, proj_b, x, out, MROWS, 1024, 1024);
    ln_kernel<<<MROWS, 256, 0, stream>>>(out, ln2_w, ln2_b, hbuf);
    // FC1: 128x128, grid 32x32 = 1024 blocks
    mgemm<128,128,true,false,true,true><<<dim3(32, 32), 256, 0, stream>>>(
        hbuf, wfc1, fc1_b, nullptr, mlp1, MROWS, 4096, 1024);
    // FC2: 64x128, grid 8x64 = 512 blocks
    mgemm<64,128,true,true,false,false><<<dim3(8, 64), 256, 0, stream>>>(
        mlp1, wfc2, fc2_b, out, out, MROWS, 1024, 4096);
}

// Round 17
// 210.579 us; speedup vs baseline: 1.0406x; 1.0406x over previous
//
#include <hip/hip_runtime.h>
#include <hip/hip_bf16.h>
#include <math.h>
#include <stdint.h>

#define SEQ 1024
#define CDIM 1024
#define NHEAD 16
#define HIDDEN 4096
#define BATCH 4
#define MROWS (BATCH*SEQ)   // 4096

using bf16x8 = __attribute__((ext_vector_type(8))) short;
using f32x4  = __attribute__((ext_vector_type(4))) float;

__device__ __forceinline__ short f2bf(float f) {
    union { float f; uint32_t u; } c; c.f = f;
    const uint32_t u = c.u + 0x7FFFu + ((c.u >> 16) & 1u);
    return (short)(u >> 16);
}

// tanh-form GELU: |err vs exact-erf GELU| < 3e-3, ~8 VALU vs erff's ~25.
__device__ __forceinline__ float gelu_fast(float x) {
    const float y = 0.7978845608f * x * (1.0f + 0.044715f * x * x);
    return x / (1.0f + __expf(-2.0f * y));
}

__device__ __forceinline__ void gload_lds16(const short* g, short* lds) {
    __builtin_amdgcn_global_load_lds(
        (const __attribute__((address_space(1))) void*)(uintptr_t)g,
        (__attribute__((address_space(3))) void*)(uintptr_t)lds,
        16, 0, 0);
}

// ------- merged weight fp32->bf16 conversion + LN1 (independent work) -------
__global__ void cvt_ln1_kernel(const float* __restrict__ qkv_w, const float* __restrict__ proj_w,
                               const float* __restrict__ fc1_w, const float* __restrict__ fc2_w,
                               short* __restrict__ wq, short* __restrict__ wp,
                               short* __restrict__ w1, short* __restrict__ w2,
                               const float* __restrict__ x, const float* __restrict__ ln1_w,
                               const float* __restrict__ ln1_b, short* __restrict__ hbuf) {
    const int blk = blockIdx.x;
    if (blk < 6144) {                    // weight conversion: 256 thr x 8 elems
        const float* in; short* out; size_t base;
        if (blk < 1536)      { in = qkv_w;  out = wq; base = (size_t)blk * 2048; }
        else if (blk < 2048) { in = proj_w; out = wp; base = (size_t)(blk - 1536) * 2048; }
        else if (blk < 4096) { in = fc1_w;  out = w1; base = (size_t)(blk - 2048) * 2048; }
        else                 { in = fc2_w;  out = w2; base = (size_t)(blk - 4096) * 2048; }
        const size_t i = base + (size_t)threadIdx.x * 8;
        const float4 a = *(const float4*)(in + i);
        const float4 b = *(const float4*)(in + i + 4);
        bf16x8 s;
        s[0] = f2bf(a.x); s[1] = f2bf(a.y); s[2] = f2bf(a.z); s[3] = f2bf(a.w);
        s[4] = f2bf(b.x); s[5] = f2bf(b.y); s[6] = f2bf(b.z); s[7] = f2bf(b.w);
        *(bf16x8*)(out + i) = s;
        return;
    }
    // LN1: one block per row
    const int row = blk - 6144;
    const int t = threadIdx.x;
    const float4* xr = (const float4*)(x + (size_t)row * CDIM);
    float4 v = xr[t];
    float s  = v.x + v.y + v.z + v.w;
    float sq = v.x*v.x + v.y*v.y + v.z*v.z + v.w*v.w;
    #pragma unroll
    for (int off = 32; off; off >>= 1) {
        s  += __shfl_down(s, off);
        sq += __shfl_down(sq, off);
    }
    __shared__ float ss[4], ssq[4];
    const int wid = t >> 6, lane = t & 63;
    if (lane == 0) { ss[wid] = s; ssq[wid] = sq; }
    __syncthreads();
    s  = ss[0] + ss[1] + ss[2] + ss[3];
    sq = ssq[0] + ssq[1] + ssq[2] + ssq[3];
    const float mu  = s * (1.0f / CDIM);
    const float var = sq * (1.0f / CDIM) - mu * mu;
    const float rs  = rsqrtf(var + 1e-5f);
    const float4 wv = ((const float4*)ln1_w)[t];
    const float4 bv = ((const float4*)ln1_b)[t];
    short4 o;
    o.x = f2bf((v.x - mu) * rs * wv.x + bv.x);
    o.y = f2bf((v.y - mu) * rs * wv.y + bv.y);
    o.z = f2bf((v.z - mu) * rs * wv.z + bv.z);
    o.w = f2bf((v.w - mu) * rs * wv.w + bv.w);
    *(short4*)(hbuf + (size_t)row * CDIM + t * 4) = o;
}

// ---------------- LayerNorm (LN2) ----------------
__global__ void ln_kernel(const float* __restrict__ x, const float* __restrict__ w,
                          const float* __restrict__ b, short* __restrict__ out) {
    const int row = blockIdx.x;
    const int t = threadIdx.x;
    const float4* xr = (const float4*)(x + (size_t)row * CDIM);
    float4 v = xr[t];
    float s  = v.x + v.y + v.z + v.w;
    float sq = v.x*v.x + v.y*v.y + v.z*v.z + v.w*v.w;
    #pragma unroll
    for (int off = 32; off; off >>= 1) {
        s  += __shfl_down(s, off);
        sq += __shfl_down(sq, off);
    }
    __shared__ float ss[4], ssq[4];
    const int wid = t >> 6, lane = t & 63;
    if (lane == 0) { ss[wid] = s; ssq[wid] = sq; }
    __syncthreads();
    s  = ss[0] + ss[1] + ss[2] + ss[3];
    sq = ssq[0] + ssq[1] + ssq[2] + ssq[3];
    const float mu  = s * (1.0f / CDIM);
    const float var = sq * (1.0f / CDIM) - mu * mu;
    const float rs  = rsqrtf(var + 1e-5f);
    const float4 wv = ((const float4*)w)[t];
    const float4 bv = ((const float4*)b)[t];
    short4 o;
    o.x = f2bf((v.x - mu) * rs * wv.x + bv.x);
    o.y = f2bf((v.y - mu) * rs * wv.y + bv.y);
    o.z = f2bf((v.z - mu) * rs * wv.z + bv.z);
    o.w = f2bf((v.w - mu) * rs * wv.w + bv.w);
    *(short4*)(out + (size_t)row * CDIM + t * 4) = o;
}

// ===== bf16 MFMA GEMM: BMxBN tile, 256 thr / 4 waves (2x2), 3-buffer
// counted-vmcnt loop, LDS swizzle both sides.
template<int BM, int BN, bool BIAS, bool RES, bool GELU_, bool OUTBF16>
__global__ __launch_bounds__(256) void mgemm(
    const short* __restrict__ A, const short* __restrict__ B,
    const float* __restrict__ bias, const float* __restrict__ res,
    void* __restrict__ Cv, int M, int N, int K)
{
    constexpr int MF = BM / 32;          // frags per wave (M)
    constexpr int NF = BN / 32;          // frags per wave (N)
    constexpr int CA = BM / 64;          // A gload chunks per wave
    constexpr int CB = BN / 64;          // B gload chunks per wave
    __shared__ __align__(16) short As[3][BM * 32];
    __shared__ __align__(16) short Bs[3][BN * 32];
    const int t = threadIdx.x;
    const int w = t >> 6, l = t & 63;

    const int gx = gridDim.x;
    const int nwg = gx * gridDim.y;
    const int lid = blockIdx.y * gx + blockIdx.x;
    const int swzb = (lid & 7) * (nwg >> 3) + (lid >> 3);
    const int bx = swzb % gx, by = swzb / gx;
    const int m0 = by * BM, n0 = bx * BN;

    const int wrow = (w >> 1) * (BM / 2);
    const int wcol = (w & 1) * (BN / 2);

    const int sk8 = ((l & 3) ^ ((l >> 3) & 3)) * 8;
    const short* agp = A + (size_t)(m0 + w * 16 * CA + (l >> 2)) * K + sk8;
    const short* bgp = B + (size_t)(n0 + w * 16 * CB + (l >> 2)) * K + sk8;

    const int fr = l & 15;
    const int rk = ((l >> 4) ^ ((fr >> 1) & 3)) * 8;
    int aoff[MF], boff[NF];
    #pragma unroll
    for (int m = 0; m < MF; ++m) aoff[m] = (wrow + m * 16 + fr) * 32 + rk;
    #pragma unroll
    for (int n = 0; n < NF; ++n) boff[n] = (wcol + n * 16 + fr) * 32 + rk;

    auto stage = [&](int k0, int buf) {
        #pragma unroll
        for (int c = 0; c < CA; ++c)
            gload_lds16(agp + (size_t)(c * 16) * K + k0, &As[buf][(w * CA + c) * 512]);
        #pragma unroll
        for (int c = 0; c < CB; ++c)
            gload_lds16(bgp + (size_t)(c * 16) * K + k0, &Bs[buf][(w * CB + c) * 512]);
    };

    f32x4 acc[MF][NF] = {};
    const int T = K / 32;
    stage(0, 0);
    stage(32, 1);
    int cur = 0;
    for (int kt = 0; kt < T; ++kt) {
        if (kt < T - 1) {
            if constexpr (CA + CB == 4) asm volatile("s_waitcnt vmcnt(4)" ::: "memory");
            else                        asm volatile("s_waitcnt vmcnt(3)" ::: "memory");
        } else {
            asm volatile("s_waitcnt vmcnt(0)" ::: "memory");
        }
        __builtin_amdgcn_s_barrier();
        if (kt + 2 < T) {
            int nb = kt + 2; nb -= (nb >= 3) ? ((nb / 3) * 3) : 0;   // (kt+2)%3
            stage((kt + 2) * 32, nb);
        }
        bf16x8 af[MF], bfr[NF];
        #pragma unroll
        for (int m = 0; m < MF; ++m) af[m]  = *(const bf16x8*)&As[cur][aoff[m]];
        #pragma unroll
        for (int n = 0; n < NF; ++n) bfr[n] = *(const bf16x8*)&Bs[cur][boff[n]];
        #pragma unroll
        for (int m = 0; m < MF; ++m)
            #pragma unroll
            for (int n = 0; n < NF; ++n)
                acc[m][n] = __builtin_amdgcn_mfma_f32_16x16x32_bf16(af[m], bfr[n], acc[m][n], 0, 0, 0);
        cur = (cur == 2) ? 0 : cur + 1;
    }

    const int lr4 = (l >> 4) * 4, lc = l & 15;
    #pragma unroll
    for (int m = 0; m < MF; ++m) {
        #pragma unroll
        for (int n = 0; n < NF; ++n) {
            const int col = n0 + wcol + n * 16 + lc;
            const float bv = BIAS ? bias[col] : 0.0f;
            #pragma unroll
            for (int r = 0; r < 4; ++r) {
                const int row = m0 + wrow + m * 16 + lr4 + r;
                float v = acc[m][n][r] + bv;
                if (GELU_) v = gelu_fast(v);
                if (RES)   v += res[(size_t)row * N + col];
                if (OUTBF16) ((short*)Cv)[(size_t)row * N + col] = f2bf(v);
                else         ((float*)Cv)[(size_t)row * N + col] = v;
            }
        }
    }
}

// ===== QKV GEMM: 128x128 mgemm body + Q/K/V epilogue (grid 24x32 = 768) =====
__global__ __launch_bounds__(256) void qkv_m(
    const short* __restrict__ A, const short* __restrict__ B,
    short* __restrict__ qkvb, short* __restrict__ VT, int K)
{
    __shared__ __align__(16) short As[3][128 * 32];
    __shared__ __align__(16) short Bs[3][128 * 32];
    const int t = threadIdx.x;
    const int w = t >> 6, l = t & 63;

    const int gx = gridDim.x;                 // 24
    const int nwg = gx * gridDim.y;           // 768
    const int lid = blockIdx.y * gx + blockIdx.x;
    const int swzb = (lid & 7) * (nwg >> 3) + (lid >> 3);
    const int bx = swzb % gx, by = swzb / gx;
    const int m0 = by * 128, n0 = bx * 128;

    const int wrow = (w >> 1) * 64;
    const int wcol = (w & 1) * 64;

    const int sk8 = ((l & 3) ^ ((l >> 3) & 3)) * 8;
    const short* agp = A + (size_t)(m0 + w * 32 + (l >> 2)) * K + sk8;
    const short* bgp = B + (size_t)(n0 + w * 32 + (l >> 2)) * K + sk8;

    const int fr = l & 15;
    const int rk = ((l >> 4) ^ ((fr >> 1) & 3)) * 8;
    int aoff[4], boff[4];
    #pragma unroll
    for (int m = 0; m < 4; ++m) aoff[m] = (wrow + m * 16 + fr) * 32 + rk;
    #pragma unroll
    for (int n = 0; n < 4; ++n) boff[n] = (wcol + n * 16 + fr) * 32 + rk;

    auto stage = [&](int k0, int buf) {
        #pragma unroll
        for (int c = 0; c < 2; ++c)
            gload_lds16(agp + (size_t)(c * 16) * K + k0, &As[buf][(w * 2 + c) * 512]);
        #pragma unroll
        for (int c = 0; c < 2; ++c)
            gload_lds16(bgp + (size_t)(c * 16) * K + k0, &Bs[buf][(w * 2 + c) * 512]);
    };

    f32x4 acc[4][4] = {};
    const int T = K / 32;
    stage(0, 0);
    stage(32, 1);
    int cur = 0;
    for (int kt = 0; kt < T; ++kt) {
        if (kt < T - 1) asm volatile("s_waitcnt vmcnt(4)" ::: "memory");
        else            asm volatile("s_waitcnt vmcnt(0)" ::: "memory");
        __builtin_amdgcn_s_barrier();
        if (kt + 2 < T) {
            int nb = kt + 2; nb -= (nb >= 3) ? ((nb / 3) * 3) : 0;
            stage((kt + 2) * 32, nb);
        }
        bf16x8 af[4], bfr[4];
        #pragma unroll
        for (int m = 0; m < 4; ++m) af[m]  = *(const bf16x8*)&As[cur][aoff[m]];
        #pragma unroll
        for (int n = 0; n < 4; ++n) bfr[n] = *(const bf16x8*)&Bs[cur][boff[n]];
        #pragma unroll
        for (int m = 0; m < 4; ++m)
            #pragma unroll
            for (int n = 0; n < 4; ++n)
                acc[m][n] = __builtin_amdgcn_mfma_f32_16x16x32_bf16(af[m], bfr[n], acc[m][n], 0, 0, 0);
        cur = (cur == 2) ? 0 : cur + 1;
    }

    const int lr4 = (l >> 4) * 4, lc = l & 15;
    if (n0 < 2048) {
        const float sc = (n0 < 1024) ? 0.125f : 1.0f;
        #pragma unroll
        for (int m = 0; m < 4; ++m) {
            #pragma unroll
            for (int n = 0; n < 4; ++n) {
                const int col = n0 + wcol + n * 16 + lc;
                #pragma unroll
                for (int r = 0; r < 4; ++r) {
                    const int row = m0 + wrow + m * 16 + lr4 + r;
                    qkvb[(size_t)row * 2048 + col] = f2bf(acc[m][n][r] * sc);
                }
            }
        }
    } else {
        #pragma unroll
        for (int m = 0; m < 4; ++m) {
            const int row0 = m0 + wrow + m * 16 + lr4;   // 4-aligned
            const int b = row0 >> 10, nseq = row0 & 1023;
            #pragma unroll
            for (int n = 0; n < 4; ++n) {
                const int c2 = n0 - 2048 + wcol + n * 16 + lc;
                const int h = c2 >> 6, d = c2 & 63;
                short4 v4;
                v4.x = f2bf(acc[m][n][0]); v4.y = f2bf(acc[m][n][1]);
                v4.z = f2bf(acc[m][n][2]); v4.w = f2bf(acc[m][n][3]);
                *(short4*)&VT[(((size_t)(b * 16 + h) * 64 + d) * 1024) + nseq] = v4;
            }
        }
    }
}

// ---------------- MFMA flash attention: QBLK=128, 8 waves, 512 blocks ----------------
__global__ __launch_bounds__(512) void fattn(const short* __restrict__ qkvb,
                                             const short* __restrict__ VT,
                                             short* __restrict__ o) {
    const int lid = blockIdx.y * gridDim.x + blockIdx.x;   // grid (8,64) = 512
    const int bh = ((lid >> 6) << 3) | (lid & 7);
    const int q0 = ((lid >> 3) & 7) * 128;
    const int b = bh >> 4, h = bh & 15;
    const int t = threadIdx.x, w = t >> 6, l = t & 63;

    __shared__ __align__(16) short Ks[2][64 * 64];
    __shared__ __align__(16) short Vs[2][64 * 64];
    __shared__ __align__(16) short Ps[8][1024];

    const size_t qrow = (size_t)(b * SEQ + q0 + w * 16 + (l & 15)) * 2048 + h * 64;
    bf16x8 qf[2];
    qf[0] = *(const bf16x8*)&qkvb[qrow + (l >> 4) * 8];
    qf[1] = *(const bf16x8*)&qkvb[qrow + 32 + (l >> 4) * 8];

    const int srow = l >> 3;
    const int sc16 = (l & 7) ^ (srow & 7);
    const short* Kg = qkvb + 1024 + h * 64;
    const short* Vg = VT + (size_t)bh * 64 * 1024;

    f32x4 acc[4] = {};
    float mr = -1e30f, lr = 0.0f;
    const int q = l & 15;
    const int g4 = (l >> 4) & 3;

    auto stage = [&](int kt, int buf) {
        const int kv0 = kt * 64;
        const int r0 = w * 8;
        gload_lds16(Kg + (size_t)(b * SEQ + kv0 + r0 + srow) * 2048 + sc16 * 8,
                    &Ks[buf][r0 * 64]);
        gload_lds16(Vg + (size_t)(r0 + srow) * 1024 + kv0 + sc16 * 8,
                    &Vs[buf][r0 * 64]);
    };

    stage(0, 0);
    for (int kt = 0; kt < 16; ++kt) {
        const int cur = kt & 1;
        __syncthreads();
        if (kt + 1 < 16) stage(kt + 1, cur ^ 1);

        f32x4 sacc[4];
        #pragma unroll
        for (int nt = 0; nt < 4; ++nt) {
            f32x4 z = {};
            #pragma unroll
            for (int ks = 0; ks < 2; ++ks) {
                const int row = nt * 16 + (l & 15);
                const int c16 = (ks * 4 + (l >> 4)) ^ (row & 7);
                const bf16x8 kf = *(const bf16x8*)&Ks[cur][row * 64 + c16 * 8];
                z = __builtin_amdgcn_mfma_f32_16x16x32_bf16(kf, qf[ks], z, 0, 0, 0);
            }
            sacc[nt] = z;
        }
        float tm = sacc[0][0];
        #pragma unroll
        for (int nt = 0; nt < 4; ++nt)
            #pragma unroll
            for (int r = 0; r < 4; ++r) tm = fmaxf(tm, sacc[nt][r]);
        tm = fmaxf(tm, __shfl_xor(tm, 16));
        tm = fmaxf(tm, __shfl_xor(tm, 32));
        const bool norescale = __all(tm <= mr + 8.0f);
        float fac = 1.0f;
        if (!norescale) {
            const float nm = fmaxf(mr, tm);
            fac = __expf(mr - nm);
            mr = nm;
        }
        float p[4][4];
        float ts = 0.0f;
        #pragma unroll
        for (int nt = 0; nt < 4; ++nt)
            #pragma unroll
            for (int r = 0; r < 4; ++r) {
                p[nt][r] = __expf(sacc[nt][r] - mr);
                ts += p[nt][r];
            }
        ts += __shfl_xor(ts, 16);
        ts += __shfl_xor(ts, 32);
        lr = lr * fac + ts;
        if (!norescale) {
            float facv[4];
            #pragma unroll
            for (int r = 0; r < 4; ++r)
                facv[r] = __shfl(fac, (l & 48) + g4 * 4 + r);
            #pragma unroll
            for (int nt2 = 0; nt2 < 4; ++nt2)
                #pragma unroll
                for (int r = 0; r < 4; ++r)
                    acc[nt2][r] *= facv[r];
        }
        #pragma unroll
        for (int nt = 0; nt < 4; ++nt) {
            uint32_t lo, hi;
            asm("v_cvt_pk_bf16_f32 %0, %1, %2" : "=v"(lo) : "v"(p[nt][0]), "v"(p[nt][1]));
            asm("v_cvt_pk_bf16_f32 %0, %1, %2" : "=v"(hi) : "v"(p[nt][2]), "v"(p[nt][3]));
            const int kvb = nt * 16 + g4 * 4;
            const int addr = q * 64 + (((kvb >> 3) ^ (q & 7)) << 3) + (kvb & 7);
            *(uint2*)&Ps[w][addr] = make_uint2(lo, hi);
        }
        asm volatile("s_waitcnt lgkmcnt(0)" ::: "memory");
        #pragma unroll
        for (int ks = 0; ks < 2; ++ks) {
            const int ql = l & 15;
            const bf16x8 pa = *(const bf16x8*)&Ps[w][ql * 64 + ((ks * 32 + (l >> 4) * 8) ^ ((ql & 7) << 3))];
            #pragma unroll
            for (int nt2 = 0; nt2 < 4; ++nt2) {
                const int row = nt2 * 16 + (l & 15);
                const int c16 = (ks * 4 + (l >> 4)) ^ (row & 7);
                const bf16x8 vf = *(const bf16x8*)&Vs[cur][row * 64 + c16 * 8];
                acc[nt2] = __builtin_amdgcn_mfma_f32_16x16x32_bf16(pa, vf, acc[nt2], 0, 0, 0);
            }
        }
    }
    float rcpl = 1.0f / lr;
    #pragma unroll
    for (int r = 0; r < 4; ++r) {
        const float rcp = __shfl(rcpl, (l & 48) + g4 * 4 + r);
        const int qq = q0 + w * 16 + g4 * 4 + r;
        #pragma unroll
        for (int nt2 = 0; nt2 < 4; ++nt2) {
            const int d = nt2 * 16 + (l & 15);
            o[(size_t)(b * SEQ + qq) * CDIM + h * 64 + d] = f2bf(acc[nt2][r] * rcp);
        }
    }
}

extern "C" void kernel_launch(void* const* d_in, const int* in_sizes, int n_in,
                              void* d_out, int out_size, void* d_ws, size_t ws_size,
                              hipStream_t stream) {
    const float* x      = (const float*)d_in[0];
    const float* ln1_w  = (const float*)d_in[1];
    const float* ln1_b  = (const float*)d_in[2];
    const float* qkv_w  = (const float*)d_in[3];
    const float* proj_w = (const float*)d_in[4];
    const float* proj_b = (const float*)d_in[5];
    const float* ln2_w  = (const float*)d_in[6];
    const float* ln2_b  = (const float*)d_in[7];
    const float* fc1_w  = (const float*)d_in[8];
    const float* fc1_b  = (const float*)d_in[9];
    const float* fc2_w  = (const float*)d_in[10];
    const float* fc2_b  = (const float*)d_in[11];
    float* out = (float*)d_out;

    short* ws16  = (short*)d_ws;
    short* wqkv  = ws16;
    short* wproj = ws16 + 3145728;
    short* wfc1  = ws16 + 4194304;
    short* wfc2  = ws16 + 8388608;
    char*  wsb   = (char*)d_ws;
    short* qkvb  = (short*)(wsb + (size_t)24 * 1024 * 1024);
    short* VT    = (short*)(wsb + (size_t)40 * 1024 * 1024);
    short* mlp1  = (short*)(wsb + (size_t)24 * 1024 * 1024);
    short* hbuf  = (short*)(wsb + (size_t)72 * 1024 * 1024);

    // cvt (6144 blocks) + LN1 (4096 blocks) merged
    cvt_ln1_kernel<<<6144 + MROWS, 256, 0, stream>>>(
        qkv_w, proj_w, fc1_w, fc2_w, wqkv, wproj, wfc1, wfc2,
        x, ln1_w, ln1_b, hbuf);
    // QKV: 128x128, grid 24x32 = 768 blocks
    qkv_m<<<dim3(24, 32), 256, 0, stream>>>(hbuf, wqkv, qkvb, VT, 1024);
    // attention: QBLK=128, 512 thr, grid 8x64 = 512 blocks
    fattn<<<dim3(8, 64), 512, 0, stream>>>(qkvb, VT, hbuf);
    // proj: 128x64, grid 16x32 = 512 blocks (better in-XCD A reuse)
    mgemm<128,64,true,true,false,false><<<dim3(16, 32), 256, 0, stream>>>(
        hbuf, wproj, proj_b, x, out, MROWS, 1024, 1024);
    ln_kernel<<<MROWS, 256, 0, stream>>>(out, ln2_w, ln2_b, hbuf);
    // FC1: 128x128, grid 32x32 = 1024 blocks (tanh-GELU epilogue)
    mgemm<128,128,true,false,true,true><<<dim3(32, 32), 256, 0, stream>>>(
        hbuf, wfc1, fc1_b, nullptr, mlp1, MROWS, 4096, 1024);
    // FC2: 128x64, grid 16x32 = 512 blocks
    mgemm<128,64,true,true,false,false><<<dim3(16, 32), 256, 0, stream>>>(
        mlp1, wfc2, fc2_b, out, out, MROWS, 1024, 4096);
}